// Round 8
// baseline (340.432 us; speedup 1.0000x reference)
//
#include <hip/hip_runtime.h>

#define EPS_F 1e-10f

typedef unsigned int u32;

// bf16 pack (RTN) / unpack helpers -------------------------------------------
__device__ __forceinline__ u32 bf16pair(float lo, float hi) {
  u32 a = __float_as_uint(lo);
  u32 b = __float_as_uint(hi);
  a = a + 0x7FFFu + ((a >> 16) & 1u);
  b = b + 0x7FFFu + ((b >> 16) & 1u);
  return (a >> 16) | (b & 0xFFFF0000u);
}
__device__ __forceinline__ float bf_lo(u32 u) { return __uint_as_float(u << 16); }
__device__ __forceinline__ float bf_hi(u32 u) { return __uint_as_float(u & 0xFFFF0000u); }

// accumulate helpers
__device__ __forceinline__ void acc_am(float4& am, uint4 u, float W) {
  am.x += W * bf_lo(u.x); am.y += W * bf_hi(u.x);
  am.z += W * bf_lo(u.y); am.w += W * bf_hi(u.y);
}
__device__ __forceinline__ void acc_av(float4& av, uint4 u, float Q) {
  av.x += Q * bf_lo(u.z); av.y += Q * bf_hi(u.z);
  av.z += Q * bf_lo(u.w); av.w += Q * bf_hi(u.w);
}
__device__ __forceinline__ void acc_m(float4& av, uint2 x, float W) {
  av.x += W * bf_lo(x.x); av.y += W * bf_hi(x.x);
  av.z += W * bf_lo(x.y); av.w += W * bf_hi(x.y);
}

// ===========================================================================
// k_hist_count: fused (a) per-row edge counts for all 3 matrices, (b) [tier1]
// STREAMING conversion of f32 history -> bf16 interleaved HB.
// HB[node] : 256 u32 = per lane [muh x4 | varh x4]  (1 KB/node)
// The conversion replaces the 262 MB random f32 ffield-gather (R7's FB build)
// with pure sequential traffic; later kernels gather the L3-resident HB.
// ===========================================================================
template <bool WITH_HB>
__global__ __launch_bounds__(256) void k_hist_count(
    const float* __restrict__ muh, const float* __restrict__ varh,
    u32* __restrict__ HB, int n_nodes,
    const int* __restrict__ ra, const int* __restrict__ rf,
    const int* __restrict__ rm, int* __restrict__ cnt, int nnz, int n_out) {
  int tid = blockIdx.x * blockDim.x + threadIdx.x;
  int nth = gridDim.x * blockDim.x;

  int total = 3 * nnz;
  for (int i = tid; i < total; i += nth) {
    int m = (i >= nnz) + (i >= 2 * nnz);
    int e = i - m * nnz;
    const int* rp = (m == 0) ? ra : (m == 1) ? rf : rm;
    atomicAdd(&cnt[m * n_out + rp[e]], 1);
  }

  if (WITH_HB) {
    int wave = tid >> 6, lane = tid & 63, nw = nth >> 6;
    int rpw = (n_nodes + nw - 1) / nw;
    int r0 = wave * rpw;
    int r1 = min(n_nodes, r0 + rpw);
    for (int node = r0; node < r1; ++node) {
      float4 mh = ((const float4*)(muh  + (size_t)node * 256))[lane];
      float4 vh = ((const float4*)(varh + (size_t)node * 256))[lane];
      uint4 hu;
      hu.x = bf16pair(mh.x, mh.y);
      hu.y = bf16pair(mh.z, mh.w);
      hu.z = bf16pair(vh.x, vh.y);
      hu.w = bf16pair(vh.z, vh.w);
      ((uint4*)(HB + (size_t)node * 256))[lane] = hu;
    }
  }
}

// ===========================================================================
// k_scan3: blockIdx.x = matrix index; exclusive scan of per-row counts.
// ===========================================================================
__global__ __launch_bounds__(256) void k_scan3(const int* __restrict__ cnt_all,
                                               int* __restrict__ base_all,
                                               int* __restrict__ cur_all, int n) {
  const int* cnt = cnt_all + blockIdx.x * n;
  int* base = base_all + blockIdx.x * (n + 1);
  int* cur = cur_all + blockIdx.x * n;
  __shared__ int sums[256];
  int tid = threadIdx.x;
  int chunk = (n + 255) / 256;
  int s = tid * chunk, e = min(s + chunk, n);
  int local = 0;
  for (int i = s; i < e; ++i) local += cnt[i];
  sums[tid] = local;
  __syncthreads();
  for (int off = 1; off < 256; off <<= 1) {
    int v = (tid >= off) ? sums[tid - off] : 0;
    __syncthreads();
    sums[tid] += v;
    __syncthreads();
  }
  int run = (tid == 0) ? 0 : sums[tid - 1];
  for (int i = s; i < e; ++i) {
    base[i] = run;
    cur[i] = run;
    run += cnt[i];
  }
  if (tid == 255) base[n] = sums[255];
}

// ===========================================================================
// k_pre_scatter: fused (a) CSR scatter for all 3 matrices (ffield resolved,
// madj 2x folded), (b) A/M intermediates over n_in. WITH_HB: history comes
// from the bf16 HB array (1 KB L3-resident gather) instead of 2 KB f32.
// A[row] : 256 u32 = per lane [dmu x4 | ds2 x4]   (1 KB/row)
// M[row] : 128 u32 = per lane [ms x4]             (512 B/row)
// ===========================================================================
template <bool WITH_HB>
__global__ __launch_bounds__(256) void k_pre_scatter(
    const float* __restrict__ mu, const float* __restrict__ var,
    const float* __restrict__ muh, const float* __restrict__ varh,
    const u32* __restrict__ HB,
    const int* __restrict__ ifield, const int* __restrict__ ffield,
    const int* __restrict__ ra, const int* __restrict__ ca, const float* __restrict__ va,
    const int* __restrict__ rf, const int* __restrict__ cf, const float* __restrict__ vf,
    const int* __restrict__ rm, const int* __restrict__ cm, const float* __restrict__ vm,
    int* __restrict__ cur_all, uint2* __restrict__ ord,
    u32* __restrict__ A, u32* __restrict__ M,
    int n_in, int n_out, int nnz) {
  int tid = blockIdx.x * blockDim.x + threadIdx.x;
  int nth = gridDim.x * blockDim.x;

  // --- (a) CSR scatter, grid-strided over 3*nnz ---
  int total = 3 * nnz;
  for (int i = tid; i < total; i += nth) {
    int m = (i >= nnz) + (i >= 2 * nnz);
    int e = i - m * nnz;
    const int* rp = (m == 0) ? ra : (m == 1) ? rf : rm;
    const int* cp = (m == 0) ? ca : (m == 1) ? cf : cm;
    const float* vp = (m == 0) ? va : (m == 1) ? vf : vm;
    int r = rp[e];
    int c = cp[e];
    float w = vp[e];
    if (m == 1) c = ffield[c];   // resolve field -> node id
    if (m == 2) w = 2.0f * w;
    int pos = atomicAdd(&cur_all[m * n_out + r], 1);
    ord[(size_t)m * nnz + pos] = make_uint2((u32)c, __float_as_uint(w));
  }

  // --- (b) A/M over n_in, contiguous chunks per wave ---
  int wave = tid >> 6, lane = tid & 63, nw = nth >> 6;
  int rpw = (n_in + nw - 1) / nw;
  int r0 = wave * rpw;
  int r1 = min(n_in, r0 + rpw);
  for (int row = r0; row < r1; ++row) {
    int f = ifield[row];
    float4 m  = ((const float4*)(mu  + (size_t)row * 256))[lane];
    float4 v  = ((const float4*)(var + (size_t)row * 256))[lane];
    float4 mh, vh;
    if (WITH_HB) {
      uint4 h = ((const uint4*)(HB + (size_t)f * 256))[lane];
      mh = make_float4(bf_lo(h.x), bf_hi(h.x), bf_lo(h.y), bf_hi(h.y));
      vh = make_float4(bf_lo(h.z), bf_hi(h.z), bf_lo(h.w), bf_hi(h.w));
    } else {
      mh = ((const float4*)(muh  + (size_t)f * 256))[lane];
      vh = ((const float4*)(varh + (size_t)f * 256))[lane];
    }
    float4 d, q, p;
    float s, sb, ds;
    s = sqrtf(v.x); sb = sqrtf(vh.x); ds = s - sb; d.x = m.x - mh.x; q.x = ds * ds; p.x = ds * sb;
    s = sqrtf(v.y); sb = sqrtf(vh.y); ds = s - sb; d.y = m.y - mh.y; q.y = ds * ds; p.y = ds * sb;
    s = sqrtf(v.z); sb = sqrtf(vh.z); ds = s - sb; d.z = m.z - mh.z; q.z = ds * ds; p.z = ds * sb;
    s = sqrtf(v.w); sb = sqrtf(vh.w); ds = s - sb; d.w = m.w - mh.w; q.w = ds * ds; p.w = ds * sb;
    uint4 au;
    au.x = bf16pair(d.x, d.y);
    au.y = bf16pair(d.z, d.w);
    au.z = bf16pair(q.x, q.y);
    au.w = bf16pair(q.z, q.w);
    ((uint4*)(A + (size_t)row * 256))[lane] = au;
    uint2 mu2;
    mu2.x = bf16pair(p.x, p.y);
    mu2.y = bf16pair(p.z, p.w);
    ((uint2*)(M + (size_t)row * 128))[lane] = mu2;
  }
}

// ===========================================================================
// k_agg: one wave per output row; register accumulation over all three CSR
// edge lists (4-edge unroll). Single write per output row, relu+eps fused.
// HAS_HB: fadj reads bf16 HB[f] (1 KB) instead of f32 muh/varh (2 KB).
// ===========================================================================
template <bool HAS_HB>
__global__ __launch_bounds__(256) void k_agg(
    const float* __restrict__ mu, const float* __restrict__ var,
    const float* __restrict__ muh, const float* __restrict__ varh,
    const u32* __restrict__ A, const u32* __restrict__ M,
    const u32* __restrict__ HB,
    const int* __restrict__ base_all, const uint2* __restrict__ ord,
    float* __restrict__ out0, float* __restrict__ out1, int n_out, int nnz) {
  int r = (int)((blockIdx.x * blockDim.x + threadIdx.x) >> 6);
  int lane = threadIdx.x & 63;
  if (r >= n_out) return;

  float4 msf = ((const float4*)(mu  + (size_t)r * 256))[lane];
  float4 vsf = ((const float4*)(var + (size_t)r * 256))[lane];

  float4 am = make_float4(0.f, 0.f, 0.f, 0.f);
  float4 av = make_float4(0.f, 0.f, 0.f, 0.f);

  // ---- adj: am += w*dmu[c]; av += w^2*ds2[c]  (bf16 interleaved in A) ----
  {
    const int* base = base_all;
    const uint2* o = ord;
    int b0 = base[r], b1 = base[r + 1];
    int p = b0;
    for (; p + 3 < b1; p += 4) {
      uint2 cv0 = o[p], cv1 = o[p + 1], cv2 = o[p + 2], cv3 = o[p + 3];
      uint4 u0 = ((const uint4*)(A + (size_t)cv0.x * 256))[lane];
      uint4 u1 = ((const uint4*)(A + (size_t)cv1.x * 256))[lane];
      uint4 u2 = ((const uint4*)(A + (size_t)cv2.x * 256))[lane];
      uint4 u3 = ((const uint4*)(A + (size_t)cv3.x * 256))[lane];
      float w0 = __uint_as_float(cv0.y), w1 = __uint_as_float(cv1.y);
      float w2 = __uint_as_float(cv2.y), w3 = __uint_as_float(cv3.y);
      acc_am(am, u0, w0); acc_am(am, u1, w1); acc_am(am, u2, w2); acc_am(am, u3, w3);
      acc_av(av, u0, w0 * w0); acc_av(av, u1, w1 * w1);
      acc_av(av, u2, w2 * w2); acc_av(av, u3, w3 * w3);
    }
    for (; p < b1; ++p) {
      uint2 cv0 = o[p];
      float w0 = __uint_as_float(cv0.y);
      uint4 u0 = ((const uint4*)(A + (size_t)cv0.x * 256))[lane];
      acc_am(am, u0, w0); acc_av(av, u0, w0 * w0);
    }
  }

  // ---- fadj: am += w*muh[f]; av += w^2*varh[f]  (f pre-resolved) ----
  {
    const int* base = base_all + (n_out + 1);
    const uint2* o = ord + (size_t)nnz;
    int b0 = base[r], b1 = base[r + 1];
    int p = b0;
    if (HAS_HB) {
      for (; p + 3 < b1; p += 4) {
        uint2 cv0 = o[p], cv1 = o[p + 1], cv2 = o[p + 2], cv3 = o[p + 3];
        uint4 u0 = ((const uint4*)(HB + (size_t)cv0.x * 256))[lane];
        uint4 u1 = ((const uint4*)(HB + (size_t)cv1.x * 256))[lane];
        uint4 u2 = ((const uint4*)(HB + (size_t)cv2.x * 256))[lane];
        uint4 u3 = ((const uint4*)(HB + (size_t)cv3.x * 256))[lane];
        float w0 = __uint_as_float(cv0.y), w1 = __uint_as_float(cv1.y);
        float w2 = __uint_as_float(cv2.y), w3 = __uint_as_float(cv3.y);
        acc_am(am, u0, w0); acc_am(am, u1, w1); acc_am(am, u2, w2); acc_am(am, u3, w3);
        acc_av(av, u0, w0 * w0); acc_av(av, u1, w1 * w1);
        acc_av(av, u2, w2 * w2); acc_av(av, u3, w3 * w3);
      }
      for (; p < b1; ++p) {
        uint2 cv0 = o[p];
        float w0 = __uint_as_float(cv0.y);
        uint4 u0 = ((const uint4*)(HB + (size_t)cv0.x * 256))[lane];
        acc_am(am, u0, w0); acc_av(av, u0, w0 * w0);
      }
    } else {
      for (; p + 1 < b1; p += 2) {
        uint2 cv0 = o[p], cv1 = o[p + 1];
        float w0 = __uint_as_float(cv0.y), w1 = __uint_as_float(cv1.y);
        float4 m0 = ((const float4*)(muh  + (size_t)cv0.x * 256))[lane];
        float4 v0 = ((const float4*)(varh + (size_t)cv0.x * 256))[lane];
        float4 m1 = ((const float4*)(muh  + (size_t)cv1.x * 256))[lane];
        float4 v1 = ((const float4*)(varh + (size_t)cv1.x * 256))[lane];
        float q0 = w0 * w0, q1 = w1 * w1;
        am.x += w0 * m0.x + w1 * m1.x; am.y += w0 * m0.y + w1 * m1.y;
        am.z += w0 * m0.z + w1 * m1.z; am.w += w0 * m0.w + w1 * m1.w;
        av.x += q0 * v0.x + q1 * v1.x; av.y += q0 * v0.y + q1 * v1.y;
        av.z += q0 * v0.z + q1 * v1.z; av.w += q0 * v0.w + q1 * v1.w;
      }
      if (p < b1) {
        uint2 cv0 = o[p];
        float w0 = __uint_as_float(cv0.y);
        float4 m0 = ((const float4*)(muh  + (size_t)cv0.x * 256))[lane];
        float4 v0 = ((const float4*)(varh + (size_t)cv0.x * 256))[lane];
        float q0 = w0 * w0;
        am.x += w0 * m0.x; am.y += w0 * m0.y; am.z += w0 * m0.z; am.w += w0 * m0.w;
        av.x += q0 * v0.x; av.y += q0 * v0.y; av.z += q0 * v0.z; av.w += q0 * v0.w;
      }
    }
  }

  // ---- madj: av += (2w)*ms[c]  (scale folded at scatter; bf16 in M) ----
  {
    const int* base = base_all + 2 * (n_out + 1);
    const uint2* o = ord + 2 * (size_t)nnz;
    int b0 = base[r], b1 = base[r + 1];
    int p = b0;
    for (; p + 3 < b1; p += 4) {
      uint2 cv0 = o[p], cv1 = o[p + 1], cv2 = o[p + 2], cv3 = o[p + 3];
      uint2 x0 = ((const uint2*)(M + (size_t)cv0.x * 128))[lane];
      uint2 x1 = ((const uint2*)(M + (size_t)cv1.x * 128))[lane];
      uint2 x2 = ((const uint2*)(M + (size_t)cv2.x * 128))[lane];
      uint2 x3 = ((const uint2*)(M + (size_t)cv3.x * 128))[lane];
      float w0 = __uint_as_float(cv0.y), w1 = __uint_as_float(cv1.y);
      float w2 = __uint_as_float(cv2.y), w3 = __uint_as_float(cv3.y);
      acc_m(av, x0, w0); acc_m(av, x1, w1); acc_m(av, x2, w2); acc_m(av, x3, w3);
    }
    for (; p < b1; ++p) {
      uint2 cv0 = o[p];
      float w0 = __uint_as_float(cv0.y);
      uint2 x0 = ((const uint2*)(M + (size_t)cv0.x * 128))[lane];
      acc_m(av, x0, w0);
    }
  }

  // ---- epilogue ----
  av.x = fmaxf(av.x, 0.f) + EPS_F;
  av.y = fmaxf(av.y, 0.f) + EPS_F;
  av.z = fmaxf(av.z, 0.f) + EPS_F;
  av.w = fmaxf(av.w, 0.f) + EPS_F;
  ((float4*)(out0 + (size_t)r * 512))[lane]       = msf;
  ((float4*)(out0 + (size_t)r * 512 + 256))[lane] = am;
  ((float4*)(out1 + (size_t)r * 512))[lane]       = vsf;
  ((float4*)(out1 + (size_t)r * 512 + 256))[lane] = av;
}

// ===========================================================================
// Fallback (tiny workspace): atomic scatter path, recompute variant.
// ===========================================================================
__global__ __launch_bounds__(256) void k_init_out(
    const float* __restrict__ mu, const float* __restrict__ var,
    float* __restrict__ out0, float* __restrict__ out1) {
  int r = blockIdx.x;
  int t = threadIdx.x;
  const float4 z = make_float4(0.f, 0.f, 0.f, 0.f);
  if (t < 128) {
    float4* dst = (float4*)(out0 + (size_t)r * 512);
    dst[t] = (t < 64) ? ((const float4*)(mu + (size_t)r * 256))[t] : z;
  } else {
    int u = t - 128;
    float4* dst = (float4*)(out1 + (size_t)r * 512);
    dst[u] = (u < 64) ? ((const float4*)(var + (size_t)r * 256))[u] : z;
  }
}

__global__ __launch_bounds__(256) void k_edge_adj_fb(
    const float* __restrict__ vals, const int* __restrict__ rows,
    const int* __restrict__ cols,
    const float* __restrict__ mu, const float* __restrict__ var,
    const float* __restrict__ muh, const float* __restrict__ varh,
    const int* __restrict__ ifield,
    float* __restrict__ out0, float* __restrict__ out1, int nnz) {
  int wave = (int)((blockIdx.x * blockDim.x + threadIdx.x) >> 6);
  int lane = threadIdx.x & 63;
  int nw = (int)((gridDim.x * blockDim.x) >> 6);
  for (int e = wave; e < nnz; e += nw) {
    float w = vals[e];
    int r = rows[e];
    int c = cols[e];
    int f = ifield[c];
    float4 m  = ((const float4*)(mu   + (size_t)c * 256))[lane];
    float4 v  = ((const float4*)(var  + (size_t)c * 256))[lane];
    float4 mh = ((const float4*)(muh  + (size_t)f * 256))[lane];
    float4 vh = ((const float4*)(varh + (size_t)f * 256))[lane];
    float4 xm, xv;
    float ds;
    xm.x = m.x - mh.x; ds = sqrtf(v.x) - sqrtf(vh.x); xv.x = ds * ds;
    xm.y = m.y - mh.y; ds = sqrtf(v.y) - sqrtf(vh.y); xv.y = ds * ds;
    xm.z = m.z - mh.z; ds = sqrtf(v.z) - sqrtf(vh.z); xv.z = ds * ds;
    xm.w = m.w - mh.w; ds = sqrtf(v.w) - sqrtf(vh.w); xv.w = ds * ds;
    float w2 = w * w;
    float* om = out0 + (size_t)r * 512 + 256 + lane * 4;
    float* ov = out1 + (size_t)r * 512 + 256 + lane * 4;
    atomicAdd(om + 0, w * xm.x); atomicAdd(om + 1, w * xm.y);
    atomicAdd(om + 2, w * xm.z); atomicAdd(om + 3, w * xm.w);
    atomicAdd(ov + 0, w2 * xv.x); atomicAdd(ov + 1, w2 * xv.y);
    atomicAdd(ov + 2, w2 * xv.z); atomicAdd(ov + 3, w2 * xv.w);
  }
}

__global__ __launch_bounds__(256) void k_edge_fadj_fb(
    const float* __restrict__ vals, const int* __restrict__ rows,
    const int* __restrict__ cols,
    const float* __restrict__ muh, const float* __restrict__ varh,
    const int* __restrict__ ffield,
    float* __restrict__ out0, float* __restrict__ out1, int nnz) {
  int wave = (int)((blockIdx.x * blockDim.x + threadIdx.x) >> 6);
  int lane = threadIdx.x & 63;
  int nw = (int)((gridDim.x * blockDim.x) >> 6);
  for (int e = wave; e < nnz; e += nw) {
    float w = vals[e];
    int r = rows[e];
    int f = ffield[cols[e]];
    float4 mb = ((const float4*)(muh  + (size_t)f * 256))[lane];
    float4 vb = ((const float4*)(varh + (size_t)f * 256))[lane];
    float w2 = w * w;
    float* om = out0 + (size_t)r * 512 + 256 + lane * 4;
    float* ov = out1 + (size_t)r * 512 + 256 + lane * 4;
    atomicAdd(om + 0, w * mb.x); atomicAdd(om + 1, w * mb.y);
    atomicAdd(om + 2, w * mb.z); atomicAdd(om + 3, w * mb.w);
    atomicAdd(ov + 0, w2 * vb.x); atomicAdd(ov + 1, w2 * vb.y);
    atomicAdd(ov + 2, w2 * vb.z); atomicAdd(ov + 3, w2 * vb.w);
  }
}

__global__ __launch_bounds__(256) void k_edge_madj_fb(
    const float* __restrict__ vals, const int* __restrict__ rows,
    const int* __restrict__ cols,
    const float* __restrict__ var, const float* __restrict__ varh,
    const int* __restrict__ ifield,
    float* __restrict__ out1, int nnz) {
  int wave = (int)((blockIdx.x * blockDim.x + threadIdx.x) >> 6);
  int lane = threadIdx.x & 63;
  int nw = (int)((gridDim.x * blockDim.x) >> 6);
  for (int e = wave; e < nnz; e += nw) {
    float w = 2.0f * vals[e];
    int r = rows[e];
    int c = cols[e];
    int f = ifield[c];
    float4 v  = ((const float4*)(var  + (size_t)c * 256))[lane];
    float4 vh = ((const float4*)(varh + (size_t)f * 256))[lane];
    float4 x;
    float sb;
    sb = sqrtf(vh.x); x.x = (sqrtf(v.x) - sb) * sb;
    sb = sqrtf(vh.y); x.y = (sqrtf(v.y) - sb) * sb;
    sb = sqrtf(vh.z); x.z = (sqrtf(v.z) - sb) * sb;
    sb = sqrtf(vh.w); x.w = (sqrtf(v.w) - sb) * sb;
    float* ov = out1 + (size_t)r * 512 + 256 + lane * 4;
    atomicAdd(ov + 0, w * x.x); atomicAdd(ov + 1, w * x.y);
    atomicAdd(ov + 2, w * x.z); atomicAdd(ov + 3, w * x.w);
  }
}

__global__ __launch_bounds__(256) void k_final(float* __restrict__ out1, int n_out) {
  int total = n_out * 64;
  for (int i = blockIdx.x * blockDim.x + threadIdx.x; i < total;
       i += gridDim.x * blockDim.x) {
    int r = i >> 6;
    int q = i & 63;
    float4* p = (float4*)(out1 + (size_t)r * 512 + 256) + q;
    float4 v = *p;
    v.x = fmaxf(v.x, 0.f) + EPS_F;
    v.y = fmaxf(v.y, 0.f) + EPS_F;
    v.z = fmaxf(v.z, 0.f) + EPS_F;
    v.w = fmaxf(v.w, 0.f) + EPS_F;
    *p = v;
  }
}

// ===========================================================================
extern "C" void kernel_launch(void* const* d_in, const int* in_sizes, int n_in_args,
                              void* d_out, int out_size, void* d_ws, size_t ws_size,
                              hipStream_t stream) {
  const float* mu        = (const float*)d_in[0];
  const float* var       = (const float*)d_in[1];
  const float* muh       = (const float*)d_in[2];
  const float* varh      = (const float*)d_in[3];
  const float* adj_vals  = (const float*)d_in[4];
  const float* fadj_vals = (const float*)d_in[5];
  const float* madj_vals = (const float*)d_in[6];
  const int* adj_rows    = (const int*)d_in[7];
  const int* adj_cols    = (const int*)d_in[8];
  const int* fadj_rows   = (const int*)d_in[9];
  const int* fadj_cols   = (const int*)d_in[10];
  const int* madj_rows   = (const int*)d_in[11];
  const int* madj_cols   = (const int*)d_in[12];
  const int* ifield      = (const int*)d_in[13];
  const int* ffield      = (const int*)d_in[14];

  const int n_out   = out_size / 1024;    // two outputs, 512 cols each
  const int n_in    = in_sizes[0] / 256;
  const int nnz     = in_sizes[4];
  const int n_nodes = in_sizes[2] / 256;  // mu_history rows

  float* out0 = (float*)d_out;
  float* out1 = out0 + (size_t)n_out * 512;

  // Workspace layout (u32 units): A, M, [HB], ord(uint2), cnt, base, cur
  const size_t uA = (size_t)n_in * 256;
  const size_t uM = (size_t)n_in * 128;
  const size_t uHB = (size_t)n_nodes * 256;
  const size_t uOrd = (size_t)3 * nnz * 2;
  const size_t uCnt = (size_t)3 * n_out;
  const size_t uBase = (size_t)3 * (n_out + 1);
  const size_t need2 = (uA + uM + uOrd + uCnt + uBase + uCnt) * sizeof(u32);
  const size_t need1 = need2 + uHB * sizeof(u32);

  if (ws_size >= need2) {
    const bool hb = (ws_size >= need1);
    u32* A = (u32*)d_ws;
    u32* M = A + uA;
    u32* HB = M + uM;                       // only valid if hb
    u32* tail = hb ? (HB + uHB) : (M + uM);
    uint2* ord = (uint2*)tail;
    int* cnt  = (int*)(tail + uOrd);
    int* base = cnt + uCnt;
    int* cur  = base + uBase;

    (void)hipMemsetAsync(cnt, 0, uCnt * sizeof(int), stream);
    if (hb) {
      k_hist_count<true><<<4096, 256, 0, stream>>>(muh, varh, HB, n_nodes,
                                                   adj_rows, fadj_rows, madj_rows,
                                                   cnt, nnz, n_out);
    } else {
      k_hist_count<false><<<1024, 256, 0, stream>>>(muh, varh, nullptr, n_nodes,
                                                    adj_rows, fadj_rows, madj_rows,
                                                    cnt, nnz, n_out);
    }
    k_scan3<<<3, 256, 0, stream>>>(cnt, base, cur, n_out);
    if (hb) {
      k_pre_scatter<true><<<2048, 256, 0, stream>>>(
          mu, var, muh, varh, HB, ifield, ffield,
          adj_rows, adj_cols, adj_vals, fadj_rows, fadj_cols, fadj_vals,
          madj_rows, madj_cols, madj_vals,
          cur, ord, A, M, n_in, n_out, nnz);
    } else {
      k_pre_scatter<false><<<2048, 256, 0, stream>>>(
          mu, var, muh, varh, nullptr, ifield, ffield,
          adj_rows, adj_cols, adj_vals, fadj_rows, fadj_cols, fadj_vals,
          madj_rows, madj_cols, madj_vals,
          cur, ord, A, M, n_in, n_out, nnz);
    }
    int blocks = (n_out * 64 + 255) / 256;
    if (hb) {
      k_agg<true><<<blocks, 256, 0, stream>>>(mu, var, muh, varh, A, M, HB, base, ord,
                                              out0, out1, n_out, nnz);
    } else {
      k_agg<false><<<blocks, 256, 0, stream>>>(mu, var, muh, varh, A, M, nullptr, base, ord,
                                               out0, out1, n_out, nnz);
    }
  } else {
    k_init_out<<<n_out, 256, 0, stream>>>(mu, var, out0, out1);
    k_edge_adj_fb<<<4096, 256, 0, stream>>>(adj_vals, adj_rows, adj_cols,
                                            mu, var, muh, varh, ifield, out0, out1, nnz);
    k_edge_madj_fb<<<4096, 256, 0, stream>>>(madj_vals, madj_rows, madj_cols,
                                             var, varh, ifield, out1, nnz);
    k_edge_fadj_fb<<<4096, 256, 0, stream>>>(fadj_vals, fadj_rows, fadj_cols,
                                             muh, varh, ffield, out0, out1, nnz);
    k_final<<<4096, 256, 0, stream>>>(out1, n_out);
  }
}

// Round 9
// 304.096 us; speedup vs baseline: 1.1195x; 1.1195x over previous
//
#include <hip/hip_runtime.h>

#define EPS_F 1e-10f

typedef unsigned int u32;

// bf16 pack (RTN) / unpack helpers -------------------------------------------
__device__ __forceinline__ u32 bf16pair(float lo, float hi) {
  u32 a = __float_as_uint(lo);
  u32 b = __float_as_uint(hi);
  a = a + 0x7FFFu + ((a >> 16) & 1u);
  b = b + 0x7FFFu + ((b >> 16) & 1u);
  return (a >> 16) | (b & 0xFFFF0000u);
}
__device__ __forceinline__ float bf_lo(u32 u) { return __uint_as_float(u << 16); }
__device__ __forceinline__ float bf_hi(u32 u) { return __uint_as_float(u & 0xFFFF0000u); }

__device__ __forceinline__ void acc_am(float4& am, uint4 u, float W) {
  am.x += W * bf_lo(u.x); am.y += W * bf_hi(u.x);
  am.z += W * bf_lo(u.y); am.w += W * bf_hi(u.y);
}
__device__ __forceinline__ void acc_av(float4& av, uint4 u, float Q) {
  av.x += Q * bf_lo(u.z); av.y += Q * bf_hi(u.z);
  av.z += Q * bf_lo(u.w); av.w += Q * bf_hi(u.w);
}
__device__ __forceinline__ void acc_m(float4& av, uint2 x, float W) {
  av.x += W * bf_lo(x.x); av.y += W * bf_hi(x.x);
  av.z += W * bf_lo(x.y); av.w += W * bf_hi(x.y);
}

// ===========================================================================
// k_count: per-row edge counts for all 3 matrices.
// ===========================================================================
__global__ __launch_bounds__(256) void k_count(
    const int* __restrict__ ra, const int* __restrict__ rf,
    const int* __restrict__ rm, int* __restrict__ cnt, int nnz, int n_out) {
  int total = 3 * nnz;
  for (int i = blockIdx.x * blockDim.x + threadIdx.x; i < total;
       i += gridDim.x * blockDim.x) {
    int m = (i >= nnz) + (i >= 2 * nnz);
    int e = i - m * nnz;
    const int* rp = (m == 0) ? ra : (m == 1) ? rf : rm;
    atomicAdd(&cnt[m * n_out + rp[e]], 1);
  }
}

// ===========================================================================
// k_scan3: blockIdx.x = matrix index; exclusive scan of per-row counts.
// ===========================================================================
__global__ __launch_bounds__(256) void k_scan3(const int* __restrict__ cnt_all,
                                               int* __restrict__ base_all,
                                               int* __restrict__ cur_all, int n) {
  const int* cnt = cnt_all + blockIdx.x * n;
  int* base = base_all + blockIdx.x * (n + 1);
  int* cur = cur_all + blockIdx.x * n;
  __shared__ int sums[256];
  int tid = threadIdx.x;
  int chunk = (n + 255) / 256;
  int s = tid * chunk, e = min(s + chunk, n);
  int local = 0;
  for (int i = s; i < e; ++i) local += cnt[i];
  sums[tid] = local;
  __syncthreads();
  for (int off = 1; off < 256; off <<= 1) {
    int v = (tid >= off) ? sums[tid - off] : 0;
    __syncthreads();
    sums[tid] += v;
    __syncthreads();
  }
  int run = (tid == 0) ? 0 : sums[tid - 1];
  for (int i = s; i < e; ++i) {
    base[i] = run;
    cur[i] = run;
    run += cnt[i];
  }
  if (tid == 255) base[n] = sums[255];
}

// ===========================================================================
// k_pre_scatter: fused (a) CSR scatter for all 3 matrices, (b) A/M over n_in
// (also writes the SELF halves of out0/out1 for rows < n_out, reusing the
// mu/var loads), (c) [tier1] FB over n_full. Separately balanced contiguous
// chunks; single-row bodies (low VGPR -> high occupancy).
// A[row]  : 256 u32 = per lane [dmu x4 | ds2 x4]           (1 KB/row)
// M[row]  : 128 u32 = per lane [ms x4]                     (512 B/row)
// FB[col] : 256 u32 = per lane [mu_bar x4 | var_bar x4]    (1 KB/row)
// ===========================================================================
template <bool WITH_FB>
__global__ __launch_bounds__(256) void k_pre_scatter(
    const float* __restrict__ mu, const float* __restrict__ var,
    const float* __restrict__ muh, const float* __restrict__ varh,
    const int* __restrict__ ifield, const int* __restrict__ ffield,
    const int* __restrict__ ra, const int* __restrict__ ca, const float* __restrict__ va,
    const int* __restrict__ rf, const int* __restrict__ cf, const float* __restrict__ vf,
    const int* __restrict__ rm, const int* __restrict__ cm, const float* __restrict__ vm,
    int* __restrict__ cur_all, uint2* __restrict__ ord,
    u32* __restrict__ A, u32* __restrict__ M, u32* __restrict__ FB,
    float* __restrict__ out0, float* __restrict__ out1,
    int n_in, int n_full, int n_out, int nnz) {
  int tid = blockIdx.x * blockDim.x + threadIdx.x;
  int nth = gridDim.x * blockDim.x;

  // --- (a) CSR scatter, grid-strided over 3*nnz ---
  int total = 3 * nnz;
  for (int i = tid; i < total; i += nth) {
    int m = (i >= nnz) + (i >= 2 * nnz);
    int e = i - m * nnz;
    const int* rp = (m == 0) ? ra : (m == 1) ? rf : rm;
    const int* cp = (m == 0) ? ca : (m == 1) ? cf : cm;
    const float* vp = (m == 0) ? va : (m == 1) ? vf : vm;
    int r = rp[e];
    int c = cp[e];
    float w = vp[e];
    if (!WITH_FB && m == 1) c = ffield[c];  // no FB: resolve field here
    if (m == 2) w = 2.0f * w;
    int pos = atomicAdd(&cur_all[m * n_out + r], 1);
    ord[(size_t)m * nnz + pos] = make_uint2((u32)c, __float_as_uint(w));
  }

  int wave = tid >> 6, lane = tid & 63, nw = nth >> 6;

  // --- (b) A/M over n_in + self-copy for rows < n_out ---
  {
    int rpw = (n_in + nw - 1) / nw;
    int r0 = wave * rpw;
    int r1 = min(n_in, r0 + rpw);
    for (int row = r0; row < r1; ++row) {
      int f = ifield[row];
      float4 m  = ((const float4*)(mu   + (size_t)row * 256))[lane];
      float4 v  = ((const float4*)(var  + (size_t)row * 256))[lane];
      float4 mh = ((const float4*)(muh  + (size_t)f   * 256))[lane];
      float4 vh = ((const float4*)(varh + (size_t)f   * 256))[lane];
      float4 d, q, p;
      float s, sb, ds;
      s = sqrtf(v.x); sb = sqrtf(vh.x); ds = s - sb; d.x = m.x - mh.x; q.x = ds * ds; p.x = ds * sb;
      s = sqrtf(v.y); sb = sqrtf(vh.y); ds = s - sb; d.y = m.y - mh.y; q.y = ds * ds; p.y = ds * sb;
      s = sqrtf(v.z); sb = sqrtf(vh.z); ds = s - sb; d.z = m.z - mh.z; q.z = ds * ds; p.z = ds * sb;
      s = sqrtf(v.w); sb = sqrtf(vh.w); ds = s - sb; d.w = m.w - mh.w; q.w = ds * ds; p.w = ds * sb;
      uint4 au;
      au.x = bf16pair(d.x, d.y);
      au.y = bf16pair(d.z, d.w);
      au.z = bf16pair(q.x, q.y);
      au.w = bf16pair(q.z, q.w);
      ((uint4*)(A + (size_t)row * 256))[lane] = au;
      uint2 mu2;
      mu2.x = bf16pair(p.x, p.y);
      mu2.y = bf16pair(p.z, p.w);
      ((uint2*)(M + (size_t)row * 128))[lane] = mu2;
      if (row < n_out) {
        ((float4*)(out0 + (size_t)row * 512))[lane] = m;   // mu_self
        ((float4*)(out1 + (size_t)row * 512))[lane] = v;   // var_self
      }
    }
  }

  // --- (c) FB over n_full ---
  if (WITH_FB) {
    int rpw = (n_full + nw - 1) / nw;
    int r0 = wave * rpw;
    int r1 = min(n_full, r0 + rpw);
    for (int row = r0; row < r1; ++row) {
      int f = ffield[row];
      float4 mb = ((const float4*)(muh  + (size_t)f * 256))[lane];
      float4 vb = ((const float4*)(varh + (size_t)f * 256))[lane];
      uint4 fu;
      fu.x = bf16pair(mb.x, mb.y);
      fu.y = bf16pair(mb.z, mb.w);
      fu.z = bf16pair(vb.x, vb.y);
      fu.w = bf16pair(vb.z, vb.w);
      ((uint4*)(FB + (size_t)row * 256))[lane] = fu;
    }
  }
}

// ===========================================================================
// k_agg: one wave per output row. Edge metadata for each CSR segment is
// loaded COALESCED (ord[b0+lane], 64 edges per 8B-lane load) and broadcast
// per edge via __shfl — removes the serial uniform-load chain ahead of the
// gathers. Writes only the NEIGHBOUR halves (self written by pre_scatter).
// ===========================================================================
template <bool HAS_FB>
__global__ __launch_bounds__(256) void k_agg(
    const float* __restrict__ muh, const float* __restrict__ varh,
    const u32* __restrict__ A, const u32* __restrict__ M,
    const u32* __restrict__ FB,
    const int* __restrict__ base_all, const uint2* __restrict__ ord,
    float* __restrict__ out0, float* __restrict__ out1, int n_out, int nnz) {
  int r = (int)((blockIdx.x * blockDim.x + threadIdx.x) >> 6);
  int lane = threadIdx.x & 63;
  if (r >= n_out) return;

  float4 am = make_float4(0.f, 0.f, 0.f, 0.f);
  float4 av = make_float4(0.f, 0.f, 0.f, 0.f);

  // ---- adj: am += w*dmu[c]; av += w^2*ds2[c] ----
  {
    int b0 = base_all[r], b1 = base_all[r + 1];
    const uint2* o = ord;
    for (int s = b0; s < b1; s += 64) {
      int rem = min(64, b1 - s);
      uint2 cv = (lane < rem) ? o[s + lane] : make_uint2(0u, 0u);
      int j = 0;
      for (; j + 3 < rem; j += 4) {
        int c0 = __shfl((int)cv.x, j),     c1 = __shfl((int)cv.x, j + 1);
        int c2 = __shfl((int)cv.x, j + 2), c3 = __shfl((int)cv.x, j + 3);
        float w0 = __uint_as_float((u32)__shfl((int)cv.y, j));
        float w1 = __uint_as_float((u32)__shfl((int)cv.y, j + 1));
        float w2 = __uint_as_float((u32)__shfl((int)cv.y, j + 2));
        float w3 = __uint_as_float((u32)__shfl((int)cv.y, j + 3));
        uint4 u0 = ((const uint4*)(A + (size_t)(u32)c0 * 256))[lane];
        uint4 u1 = ((const uint4*)(A + (size_t)(u32)c1 * 256))[lane];
        uint4 u2 = ((const uint4*)(A + (size_t)(u32)c2 * 256))[lane];
        uint4 u3 = ((const uint4*)(A + (size_t)(u32)c3 * 256))[lane];
        acc_am(am, u0, w0); acc_am(am, u1, w1); acc_am(am, u2, w2); acc_am(am, u3, w3);
        acc_av(av, u0, w0 * w0); acc_av(av, u1, w1 * w1);
        acc_av(av, u2, w2 * w2); acc_av(av, u3, w3 * w3);
      }
      for (; j < rem; ++j) {
        int c0 = __shfl((int)cv.x, j);
        float w0 = __uint_as_float((u32)__shfl((int)cv.y, j));
        uint4 u0 = ((const uint4*)(A + (size_t)(u32)c0 * 256))[lane];
        acc_am(am, u0, w0); acc_av(av, u0, w0 * w0);
      }
    }
  }

  // ---- fadj: am += w*mu_bar; av += w^2*var_bar ----
  {
    const int* base = base_all + (n_out + 1);
    const uint2* o = ord + (size_t)nnz;
    int b0 = base[r], b1 = base[r + 1];
    for (int s = b0; s < b1; s += 64) {
      int rem = min(64, b1 - s);
      uint2 cv = (lane < rem) ? o[s + lane] : make_uint2(0u, 0u);
      int j = 0;
      if (HAS_FB) {
        for (; j + 3 < rem; j += 4) {
          int c0 = __shfl((int)cv.x, j),     c1 = __shfl((int)cv.x, j + 1);
          int c2 = __shfl((int)cv.x, j + 2), c3 = __shfl((int)cv.x, j + 3);
          float w0 = __uint_as_float((u32)__shfl((int)cv.y, j));
          float w1 = __uint_as_float((u32)__shfl((int)cv.y, j + 1));
          float w2 = __uint_as_float((u32)__shfl((int)cv.y, j + 2));
          float w3 = __uint_as_float((u32)__shfl((int)cv.y, j + 3));
          uint4 u0 = ((const uint4*)(FB + (size_t)(u32)c0 * 256))[lane];
          uint4 u1 = ((const uint4*)(FB + (size_t)(u32)c1 * 256))[lane];
          uint4 u2 = ((const uint4*)(FB + (size_t)(u32)c2 * 256))[lane];
          uint4 u3 = ((const uint4*)(FB + (size_t)(u32)c3 * 256))[lane];
          acc_am(am, u0, w0); acc_am(am, u1, w1); acc_am(am, u2, w2); acc_am(am, u3, w3);
          acc_av(av, u0, w0 * w0); acc_av(av, u1, w1 * w1);
          acc_av(av, u2, w2 * w2); acc_av(av, u3, w3 * w3);
        }
        for (; j < rem; ++j) {
          int c0 = __shfl((int)cv.x, j);
          float w0 = __uint_as_float((u32)__shfl((int)cv.y, j));
          uint4 u0 = ((const uint4*)(FB + (size_t)(u32)c0 * 256))[lane];
          acc_am(am, u0, w0); acc_av(av, u0, w0 * w0);
        }
      } else {
        for (; j < rem; ++j) {
          int c0 = __shfl((int)cv.x, j);
          float w0 = __uint_as_float((u32)__shfl((int)cv.y, j));
          float4 m0 = ((const float4*)(muh  + (size_t)(u32)c0 * 256))[lane];
          float4 v0 = ((const float4*)(varh + (size_t)(u32)c0 * 256))[lane];
          float q0 = w0 * w0;
          am.x += w0 * m0.x; am.y += w0 * m0.y; am.z += w0 * m0.z; am.w += w0 * m0.w;
          av.x += q0 * v0.x; av.y += q0 * v0.y; av.z += q0 * v0.z; av.w += q0 * v0.w;
        }
      }
    }
  }

  // ---- madj: av += (2w)*ms[c] ----
  {
    const int* base = base_all + 2 * (n_out + 1);
    const uint2* o = ord + 2 * (size_t)nnz;
    int b0 = base[r], b1 = base[r + 1];
    for (int s = b0; s < b1; s += 64) {
      int rem = min(64, b1 - s);
      uint2 cv = (lane < rem) ? o[s + lane] : make_uint2(0u, 0u);
      int j = 0;
      for (; j + 3 < rem; j += 4) {
        int c0 = __shfl((int)cv.x, j),     c1 = __shfl((int)cv.x, j + 1);
        int c2 = __shfl((int)cv.x, j + 2), c3 = __shfl((int)cv.x, j + 3);
        float w0 = __uint_as_float((u32)__shfl((int)cv.y, j));
        float w1 = __uint_as_float((u32)__shfl((int)cv.y, j + 1));
        float w2 = __uint_as_float((u32)__shfl((int)cv.y, j + 2));
        float w3 = __uint_as_float((u32)__shfl((int)cv.y, j + 3));
        uint2 x0 = ((const uint2*)(M + (size_t)(u32)c0 * 128))[lane];
        uint2 x1 = ((const uint2*)(M + (size_t)(u32)c1 * 128))[lane];
        uint2 x2 = ((const uint2*)(M + (size_t)(u32)c2 * 128))[lane];
        uint2 x3 = ((const uint2*)(M + (size_t)(u32)c3 * 128))[lane];
        acc_m(av, x0, w0); acc_m(av, x1, w1); acc_m(av, x2, w2); acc_m(av, x3, w3);
      }
      for (; j < rem; ++j) {
        int c0 = __shfl((int)cv.x, j);
        float w0 = __uint_as_float((u32)__shfl((int)cv.y, j));
        uint2 x0 = ((const uint2*)(M + (size_t)(u32)c0 * 128))[lane];
        acc_m(av, x0, w0);
      }
    }
  }

  // ---- epilogue: neighbour halves only ----
  av.x = fmaxf(av.x, 0.f) + EPS_F;
  av.y = fmaxf(av.y, 0.f) + EPS_F;
  av.z = fmaxf(av.z, 0.f) + EPS_F;
  av.w = fmaxf(av.w, 0.f) + EPS_F;
  ((float4*)(out0 + (size_t)r * 512 + 256))[lane] = am;
  ((float4*)(out1 + (size_t)r * 512 + 256))[lane] = av;
}

// ===========================================================================
// Fallback (tiny workspace): atomic scatter path, recompute variant.
// ===========================================================================
__global__ __launch_bounds__(256) void k_init_out(
    const float* __restrict__ mu, const float* __restrict__ var,
    float* __restrict__ out0, float* __restrict__ out1) {
  int r = blockIdx.x;
  int t = threadIdx.x;
  const float4 z = make_float4(0.f, 0.f, 0.f, 0.f);
  if (t < 128) {
    float4* dst = (float4*)(out0 + (size_t)r * 512);
    dst[t] = (t < 64) ? ((const float4*)(mu + (size_t)r * 256))[t] : z;
  } else {
    int u = t - 128;
    float4* dst = (float4*)(out1 + (size_t)r * 512);
    dst[u] = (u < 64) ? ((const float4*)(var + (size_t)r * 256))[u] : z;
  }
}

__global__ __launch_bounds__(256) void k_edge_adj_fb(
    const float* __restrict__ vals, const int* __restrict__ rows,
    const int* __restrict__ cols,
    const float* __restrict__ mu, const float* __restrict__ var,
    const float* __restrict__ muh, const float* __restrict__ varh,
    const int* __restrict__ ifield,
    float* __restrict__ out0, float* __restrict__ out1, int nnz) {
  int wave = (int)((blockIdx.x * blockDim.x + threadIdx.x) >> 6);
  int lane = threadIdx.x & 63;
  int nw = (int)((gridDim.x * blockDim.x) >> 6);
  for (int e = wave; e < nnz; e += nw) {
    float w = vals[e];
    int r = rows[e];
    int c = cols[e];
    int f = ifield[c];
    float4 m  = ((const float4*)(mu   + (size_t)c * 256))[lane];
    float4 v  = ((const float4*)(var  + (size_t)c * 256))[lane];
    float4 mh = ((const float4*)(muh  + (size_t)f * 256))[lane];
    float4 vh = ((const float4*)(varh + (size_t)f * 256))[lane];
    float4 xm, xv;
    float ds;
    xm.x = m.x - mh.x; ds = sqrtf(v.x) - sqrtf(vh.x); xv.x = ds * ds;
    xm.y = m.y - mh.y; ds = sqrtf(v.y) - sqrtf(vh.y); xv.y = ds * ds;
    xm.z = m.z - mh.z; ds = sqrtf(v.z) - sqrtf(vh.z); xv.z = ds * ds;
    xm.w = m.w - mh.w; ds = sqrtf(v.w) - sqrtf(vh.w); xv.w = ds * ds;
    float w2 = w * w;
    float* om = out0 + (size_t)r * 512 + 256 + lane * 4;
    float* ov = out1 + (size_t)r * 512 + 256 + lane * 4;
    atomicAdd(om + 0, w * xm.x); atomicAdd(om + 1, w * xm.y);
    atomicAdd(om + 2, w * xm.z); atomicAdd(om + 3, w * xm.w);
    atomicAdd(ov + 0, w2 * xv.x); atomicAdd(ov + 1, w2 * xv.y);
    atomicAdd(ov + 2, w2 * xv.z); atomicAdd(ov + 3, w2 * xv.w);
  }
}

__global__ __launch_bounds__(256) void k_edge_fadj_fb(
    const float* __restrict__ vals, const int* __restrict__ rows,
    const int* __restrict__ cols,
    const float* __restrict__ muh, const float* __restrict__ varh,
    const int* __restrict__ ffield,
    float* __restrict__ out0, float* __restrict__ out1, int nnz) {
  int wave = (int)((blockIdx.x * blockDim.x + threadIdx.x) >> 6);
  int lane = threadIdx.x & 63;
  int nw = (int)((gridDim.x * blockDim.x) >> 6);
  for (int e = wave; e < nnz; e += nw) {
    float w = vals[e];
    int r = rows[e];
    int f = ffield[cols[e]];
    float4 mb = ((const float4*)(muh  + (size_t)f * 256))[lane];
    float4 vb = ((const float4*)(varh + (size_t)f * 256))[lane];
    float w2 = w * w;
    float* om = out0 + (size_t)r * 512 + 256 + lane * 4;
    float* ov = out1 + (size_t)r * 512 + 256 + lane * 4;
    atomicAdd(om + 0, w * mb.x); atomicAdd(om + 1, w * mb.y);
    atomicAdd(om + 2, w * mb.z); atomicAdd(om + 3, w * mb.w);
    atomicAdd(ov + 0, w2 * vb.x); atomicAdd(ov + 1, w2 * vb.y);
    atomicAdd(ov + 2, w2 * vb.z); atomicAdd(ov + 3, w2 * vb.w);
  }
}

__global__ __launch_bounds__(256) void k_edge_madj_fb(
    const float* __restrict__ vals, const int* __restrict__ rows,
    const int* __restrict__ cols,
    const float* __restrict__ var, const float* __restrict__ varh,
    const int* __restrict__ ifield,
    float* __restrict__ out1, int nnz) {
  int wave = (int)((blockIdx.x * blockDim.x + threadIdx.x) >> 6);
  int lane = threadIdx.x & 63;
  int nw = (int)((gridDim.x * blockDim.x) >> 6);
  for (int e = wave; e < nnz; e += nw) {
    float w = 2.0f * vals[e];
    int r = rows[e];
    int c = cols[e];
    int f = ifield[c];
    float4 v  = ((const float4*)(var  + (size_t)c * 256))[lane];
    float4 vh = ((const float4*)(varh + (size_t)f * 256))[lane];
    float4 x;
    float sb;
    sb = sqrtf(vh.x); x.x = (sqrtf(v.x) - sb) * sb;
    sb = sqrtf(vh.y); x.y = (sqrtf(v.y) - sb) * sb;
    sb = sqrtf(vh.z); x.z = (sqrtf(v.z) - sb) * sb;
    sb = sqrtf(vh.w); x.w = (sqrtf(v.w) - sb) * sb;
    float* ov = out1 + (size_t)r * 512 + 256 + lane * 4;
    atomicAdd(ov + 0, w * x.x); atomicAdd(ov + 1, w * x.y);
    atomicAdd(ov + 2, w * x.z); atomicAdd(ov + 3, w * x.w);
  }
}

__global__ __launch_bounds__(256) void k_final(float* __restrict__ out1, int n_out) {
  int total = n_out * 64;
  for (int i = blockIdx.x * blockDim.x + threadIdx.x; i < total;
       i += gridDim.x * blockDim.x) {
    int r = i >> 6;
    int q = i & 63;
    float4* p = (float4*)(out1 + (size_t)r * 512 + 256) + q;
    float4 v = *p;
    v.x = fmaxf(v.x, 0.f) + EPS_F;
    v.y = fmaxf(v.y, 0.f) + EPS_F;
    v.z = fmaxf(v.z, 0.f) + EPS_F;
    v.w = fmaxf(v.w, 0.f) + EPS_F;
    *p = v;
  }
}

// ===========================================================================
extern "C" void kernel_launch(void* const* d_in, const int* in_sizes, int n_in_args,
                              void* d_out, int out_size, void* d_ws, size_t ws_size,
                              hipStream_t stream) {
  const float* mu        = (const float*)d_in[0];
  const float* var       = (const float*)d_in[1];
  const float* muh       = (const float*)d_in[2];
  const float* varh      = (const float*)d_in[3];
  const float* adj_vals  = (const float*)d_in[4];
  const float* fadj_vals = (const float*)d_in[5];
  const float* madj_vals = (const float*)d_in[6];
  const int* adj_rows    = (const int*)d_in[7];
  const int* adj_cols    = (const int*)d_in[8];
  const int* fadj_rows   = (const int*)d_in[9];
  const int* fadj_cols   = (const int*)d_in[10];
  const int* madj_rows   = (const int*)d_in[11];
  const int* madj_cols   = (const int*)d_in[12];
  const int* ifield      = (const int*)d_in[13];
  const int* ffield      = (const int*)d_in[14];

  const int n_out  = out_size / 1024;    // two outputs, 512 cols each
  const int n_in   = in_sizes[0] / 256;
  const int nnz    = in_sizes[4];
  const int n_full = in_sizes[14];       // ffield length

  float* out0 = (float*)d_out;
  float* out1 = out0 + (size_t)n_out * 512;

  // Workspace layout (u32 units): A, M, [FB], ord(uint2), cnt, base, cur
  const size_t uA = (size_t)n_in * 256;
  const size_t uM = (size_t)n_in * 128;
  const size_t uFB = (size_t)n_full * 256;
  const size_t uOrd = (size_t)3 * nnz * 2;
  const size_t uCnt = (size_t)3 * n_out;
  const size_t uBase = (size_t)3 * (n_out + 1);
  const size_t need2 = (uA + uM + uOrd + uCnt + uBase + uCnt) * sizeof(u32);
  const size_t need1 = need2 + uFB * sizeof(u32);

  if (ws_size >= need2) {
    const bool fb = (ws_size >= need1);
    u32* A = (u32*)d_ws;
    u32* M = A + uA;
    u32* FB = M + uM;                       // only valid if fb
    u32* tail = fb ? (FB + uFB) : (M + uM);
    uint2* ord = (uint2*)tail;
    int* cnt  = (int*)(tail + uOrd);
    int* base = cnt + uCnt;
    int* cur  = base + uBase;

    (void)hipMemsetAsync(cnt, 0, uCnt * sizeof(int), stream);
    k_count<<<1024, 256, 0, stream>>>(adj_rows, fadj_rows, madj_rows, cnt, nnz, n_out);
    k_scan3<<<3, 256, 0, stream>>>(cnt, base, cur, n_out);
    if (fb) {
      k_pre_scatter<true><<<2048, 256, 0, stream>>>(
          mu, var, muh, varh, ifield, ffield,
          adj_rows, adj_cols, adj_vals, fadj_rows, fadj_cols, fadj_vals,
          madj_rows, madj_cols, madj_vals,
          cur, ord, A, M, FB, out0, out1, n_in, n_full, n_out, nnz);
    } else {
      k_pre_scatter<false><<<2048, 256, 0, stream>>>(
          mu, var, muh, varh, ifield, ffield,
          adj_rows, adj_cols, adj_vals, fadj_rows, fadj_cols, fadj_vals,
          madj_rows, madj_cols, madj_vals,
          cur, ord, A, M, nullptr, out0, out1, n_in, n_full, n_out, nnz);
    }
    int blocks = (n_out * 64 + 255) / 256;
    if (fb) {
      k_agg<true><<<blocks, 256, 0, stream>>>(muh, varh, A, M, FB, base, ord,
                                              out0, out1, n_out, nnz);
    } else {
      k_agg<false><<<blocks, 256, 0, stream>>>(muh, varh, A, M, nullptr, base, ord,
                                               out0, out1, n_out, nnz);
    }
  } else {
    k_init_out<<<n_out, 256, 0, stream>>>(mu, var, out0, out1);
    k_edge_adj_fb<<<4096, 256, 0, stream>>>(adj_vals, adj_rows, adj_cols,
                                            mu, var, muh, varh, ifield, out0, out1, nnz);
    k_edge_madj_fb<<<4096, 256, 0, stream>>>(madj_vals, madj_rows, madj_cols,
                                             var, varh, ifield, out1, nnz);
    k_edge_fadj_fb<<<4096, 256, 0, stream>>>(fadj_vals, fadj_rows, fadj_cols,
                                             muh, varh, ffield, out0, out1, nnz);
    k_final<<<4096, 256, 0, stream>>>(out1, n_out);
  }
}

// Round 11
// 303.930 us; speedup vs baseline: 1.1201x; 1.0005x over previous
//
#include <hip/hip_runtime.h>

#define EPS_F 1e-10f

typedef unsigned int u32;
typedef float __attribute__((ext_vector_type(4))) f32x4;

// bf16 pack (RTN) / unpack helpers -------------------------------------------
__device__ __forceinline__ u32 bf16pair(float lo, float hi) {
  u32 a = __float_as_uint(lo);
  u32 b = __float_as_uint(hi);
  a = a + 0x7FFFu + ((a >> 16) & 1u);
  b = b + 0x7FFFu + ((b >> 16) & 1u);
  return (a >> 16) | (b & 0xFFFF0000u);
}
__device__ __forceinline__ float bf_lo(u32 u) { return __uint_as_float(u << 16); }
__device__ __forceinline__ float bf_hi(u32 u) { return __uint_as_float(u & 0xFFFF0000u); }

__device__ __forceinline__ void acc_am(float4& am, uint4 u, float W) {
  am.x += W * bf_lo(u.x); am.y += W * bf_hi(u.x);
  am.z += W * bf_lo(u.y); am.w += W * bf_hi(u.y);
}
__device__ __forceinline__ void acc_av(float4& av, uint4 u, float Q) {
  av.x += Q * bf_lo(u.z); av.y += Q * bf_hi(u.z);
  av.z += Q * bf_lo(u.w); av.w += Q * bf_hi(u.w);
}
__device__ __forceinline__ void acc_m(float4& av, uint2 x, float W) {
  av.x += W * bf_lo(x.x); av.y += W * bf_hi(x.x);
  av.z += W * bf_lo(x.y); av.w += W * bf_hi(x.y);
}

// stream-once helpers via native ext_vector_type (builtin requires it)
__device__ __forceinline__ float4 ntload4(const float* p) {
  f32x4 t = __builtin_nontemporal_load((const f32x4*)p);
  return make_float4(t.x, t.y, t.z, t.w);
}
__device__ __forceinline__ void ntstore4(float* p, float4 v) {
  f32x4 t = {v.x, v.y, v.z, v.w};
  __builtin_nontemporal_store(t, (f32x4*)p);
}

// ===========================================================================
// k_count: per-row edge counts for all 3 matrices.
// ===========================================================================
__global__ __launch_bounds__(256) void k_count(
    const int* __restrict__ ra, const int* __restrict__ rf,
    const int* __restrict__ rm, int* __restrict__ cnt, int nnz, int n_out) {
  int total = 3 * nnz;
  for (int i = blockIdx.x * blockDim.x + threadIdx.x; i < total;
       i += gridDim.x * blockDim.x) {
    int m = (i >= nnz) + (i >= 2 * nnz);
    int e = i - m * nnz;
    const int* rp = (m == 0) ? ra : (m == 1) ? rf : rm;
    atomicAdd(&cnt[m * n_out + rp[e]], 1);
  }
}

// ===========================================================================
// k_scan3: blockIdx.x = matrix index; exclusive scan of per-row counts.
// ===========================================================================
__global__ __launch_bounds__(256) void k_scan3(const int* __restrict__ cnt_all,
                                               int* __restrict__ base_all,
                                               int* __restrict__ cur_all, int n) {
  const int* cnt = cnt_all + blockIdx.x * n;
  int* base = base_all + blockIdx.x * (n + 1);
  int* cur = cur_all + blockIdx.x * n;
  __shared__ int sums[256];
  int tid = threadIdx.x;
  int chunk = (n + 255) / 256;
  int s = tid * chunk, e = min(s + chunk, n);
  int local = 0;
  for (int i = s; i < e; ++i) local += cnt[i];
  sums[tid] = local;
  __syncthreads();
  for (int off = 1; off < 256; off <<= 1) {
    int v = (tid >= off) ? sums[tid - off] : 0;
    __syncthreads();
    sums[tid] += v;
    __syncthreads();
  }
  int run = (tid == 0) ? 0 : sums[tid - 1];
  for (int i = s; i < e; ++i) {
    base[i] = run;
    cur[i] = run;
    run += cnt[i];
  }
  if (tid == 255) base[n] = sums[255];
}

// ===========================================================================
// k_pre_scatter: fused (a) CSR scatter, (b) A/M over n_in (+ self halves of
// out0/out1 for rows < n_out, non-temporal), (c) [tier1] FB over n_full.
// mu/var loads are non-temporal (read-once) so they don't evict the gather
// arrays (history now; A/M/FB for k_agg later) from L2/L3.
// ===========================================================================
template <bool WITH_FB>
__global__ __launch_bounds__(256) void k_pre_scatter(
    const float* __restrict__ mu, const float* __restrict__ var,
    const float* __restrict__ muh, const float* __restrict__ varh,
    const int* __restrict__ ifield, const int* __restrict__ ffield,
    const int* __restrict__ ra, const int* __restrict__ ca, const float* __restrict__ va,
    const int* __restrict__ rf, const int* __restrict__ cf, const float* __restrict__ vf,
    const int* __restrict__ rm, const int* __restrict__ cm, const float* __restrict__ vm,
    int* __restrict__ cur_all, uint2* __restrict__ ord,
    u32* __restrict__ A, u32* __restrict__ M, u32* __restrict__ FB,
    float* __restrict__ out0, float* __restrict__ out1,
    int n_in, int n_full, int n_out, int nnz) {
  int tid = blockIdx.x * blockDim.x + threadIdx.x;
  int nth = gridDim.x * blockDim.x;

  // --- (a) CSR scatter, grid-strided over 3*nnz ---
  int total = 3 * nnz;
  for (int i = tid; i < total; i += nth) {
    int m = (i >= nnz) + (i >= 2 * nnz);
    int e = i - m * nnz;
    const int* rp = (m == 0) ? ra : (m == 1) ? rf : rm;
    const int* cp = (m == 0) ? ca : (m == 1) ? cf : cm;
    const float* vp = (m == 0) ? va : (m == 1) ? vf : vm;
    int r = rp[e];
    int c = cp[e];
    float w = vp[e];
    if (!WITH_FB && m == 1) c = ffield[c];
    if (m == 2) w = 2.0f * w;
    int pos = atomicAdd(&cur_all[m * n_out + r], 1);
    ord[(size_t)m * nnz + pos] = make_uint2((u32)c, __float_as_uint(w));
  }

  int wave = tid >> 6, lane = tid & 63, nw = nth >> 6;

  // --- (b) A/M over n_in + non-temporal self-copy for rows < n_out ---
  {
    int rpw = (n_in + nw - 1) / nw;
    int r0 = wave * rpw;
    int r1 = min(n_in, r0 + rpw);
    for (int row = r0; row < r1; ++row) {
      int f = ifield[row];
      float4 m  = ntload4(mu  + (size_t)row * 256 + lane * 4);
      float4 v  = ntload4(var + (size_t)row * 256 + lane * 4);
      float4 mh = ((const float4*)(muh  + (size_t)f * 256))[lane];
      float4 vh = ((const float4*)(varh + (size_t)f * 256))[lane];
      float4 d, q, p;
      float s, sb, ds;
      s = sqrtf(v.x); sb = sqrtf(vh.x); ds = s - sb; d.x = m.x - mh.x; q.x = ds * ds; p.x = ds * sb;
      s = sqrtf(v.y); sb = sqrtf(vh.y); ds = s - sb; d.y = m.y - mh.y; q.y = ds * ds; p.y = ds * sb;
      s = sqrtf(v.z); sb = sqrtf(vh.z); ds = s - sb; d.z = m.z - mh.z; q.z = ds * ds; p.z = ds * sb;
      s = sqrtf(v.w); sb = sqrtf(vh.w); ds = s - sb; d.w = m.w - mh.w; q.w = ds * ds; p.w = ds * sb;
      uint4 au;
      au.x = bf16pair(d.x, d.y);
      au.y = bf16pair(d.z, d.w);
      au.z = bf16pair(q.x, q.y);
      au.w = bf16pair(q.z, q.w);
      ((uint4*)(A + (size_t)row * 256))[lane] = au;
      uint2 mu2;
      mu2.x = bf16pair(p.x, p.y);
      mu2.y = bf16pair(p.z, p.w);
      ((uint2*)(M + (size_t)row * 128))[lane] = mu2;
      if (row < n_out) {
        ntstore4(out0 + (size_t)row * 512 + lane * 4, m);   // mu_self
        ntstore4(out1 + (size_t)row * 512 + lane * 4, v);   // var_self
      }
    }
  }

  // --- (c) FB over n_full ---
  if (WITH_FB) {
    int rpw = (n_full + nw - 1) / nw;
    int r0 = wave * rpw;
    int r1 = min(n_full, r0 + rpw);
    for (int row = r0; row < r1; ++row) {
      int f = ffield[row];
      float4 mb = ((const float4*)(muh  + (size_t)f * 256))[lane];
      float4 vb = ((const float4*)(varh + (size_t)f * 256))[lane];
      uint4 fu;
      fu.x = bf16pair(mb.x, mb.y);
      fu.y = bf16pair(mb.z, mb.w);
      fu.z = bf16pair(vb.x, vb.y);
      fu.w = bf16pair(vb.z, vb.w);
      ((uint4*)(FB + (size_t)row * 256))[lane] = fu;
    }
  }
}

// ===========================================================================
// k_agg: one wave per output row; coalesced ord loads + __shfl broadcast;
// 4-edge unroll. Neighbour-half writes are non-temporal (never re-read).
// ===========================================================================
template <bool HAS_FB>
__global__ __launch_bounds__(256) void k_agg(
    const float* __restrict__ muh, const float* __restrict__ varh,
    const u32* __restrict__ A, const u32* __restrict__ M,
    const u32* __restrict__ FB,
    const int* __restrict__ base_all, const uint2* __restrict__ ord,
    float* __restrict__ out0, float* __restrict__ out1, int n_out, int nnz) {
  int r = (int)((blockIdx.x * blockDim.x + threadIdx.x) >> 6);
  int lane = threadIdx.x & 63;
  if (r >= n_out) return;

  float4 am = make_float4(0.f, 0.f, 0.f, 0.f);
  float4 av = make_float4(0.f, 0.f, 0.f, 0.f);

  // ---- adj ----
  {
    int b0 = base_all[r], b1 = base_all[r + 1];
    const uint2* o = ord;
    for (int s = b0; s < b1; s += 64) {
      int rem = min(64, b1 - s);
      uint2 cv = (lane < rem) ? o[s + lane] : make_uint2(0u, 0u);
      int j = 0;
      for (; j + 3 < rem; j += 4) {
        int c0 = __shfl((int)cv.x, j),     c1 = __shfl((int)cv.x, j + 1);
        int c2 = __shfl((int)cv.x, j + 2), c3 = __shfl((int)cv.x, j + 3);
        float w0 = __uint_as_float((u32)__shfl((int)cv.y, j));
        float w1 = __uint_as_float((u32)__shfl((int)cv.y, j + 1));
        float w2 = __uint_as_float((u32)__shfl((int)cv.y, j + 2));
        float w3 = __uint_as_float((u32)__shfl((int)cv.y, j + 3));
        uint4 u0 = ((const uint4*)(A + (size_t)(u32)c0 * 256))[lane];
        uint4 u1 = ((const uint4*)(A + (size_t)(u32)c1 * 256))[lane];
        uint4 u2 = ((const uint4*)(A + (size_t)(u32)c2 * 256))[lane];
        uint4 u3 = ((const uint4*)(A + (size_t)(u32)c3 * 256))[lane];
        acc_am(am, u0, w0); acc_am(am, u1, w1); acc_am(am, u2, w2); acc_am(am, u3, w3);
        acc_av(av, u0, w0 * w0); acc_av(av, u1, w1 * w1);
        acc_av(av, u2, w2 * w2); acc_av(av, u3, w3 * w3);
      }
      for (; j < rem; ++j) {
        int c0 = __shfl((int)cv.x, j);
        float w0 = __uint_as_float((u32)__shfl((int)cv.y, j));
        uint4 u0 = ((const uint4*)(A + (size_t)(u32)c0 * 256))[lane];
        acc_am(am, u0, w0); acc_av(av, u0, w0 * w0);
      }
    }
  }

  // ---- fadj ----
  {
    const int* base = base_all + (n_out + 1);
    const uint2* o = ord + (size_t)nnz;
    int b0 = base[r], b1 = base[r + 1];
    for (int s = b0; s < b1; s += 64) {
      int rem = min(64, b1 - s);
      uint2 cv = (lane < rem) ? o[s + lane] : make_uint2(0u, 0u);
      int j = 0;
      if (HAS_FB) {
        for (; j + 3 < rem; j += 4) {
          int c0 = __shfl((int)cv.x, j),     c1 = __shfl((int)cv.x, j + 1);
          int c2 = __shfl((int)cv.x, j + 2), c3 = __shfl((int)cv.x, j + 3);
          float w0 = __uint_as_float((u32)__shfl((int)cv.y, j));
          float w1 = __uint_as_float((u32)__shfl((int)cv.y, j + 1));
          float w2 = __uint_as_float((u32)__shfl((int)cv.y, j + 2));
          float w3 = __uint_as_float((u32)__shfl((int)cv.y, j + 3));
          uint4 u0 = ((const uint4*)(FB + (size_t)(u32)c0 * 256))[lane];
          uint4 u1 = ((const uint4*)(FB + (size_t)(u32)c1 * 256))[lane];
          uint4 u2 = ((const uint4*)(FB + (size_t)(u32)c2 * 256))[lane];
          uint4 u3 = ((const uint4*)(FB + (size_t)(u32)c3 * 256))[lane];
          acc_am(am, u0, w0); acc_am(am, u1, w1); acc_am(am, u2, w2); acc_am(am, u3, w3);
          acc_av(av, u0, w0 * w0); acc_av(av, u1, w1 * w1);
          acc_av(av, u2, w2 * w2); acc_av(av, u3, w3 * w3);
        }
        for (; j < rem; ++j) {
          int c0 = __shfl((int)cv.x, j);
          float w0 = __uint_as_float((u32)__shfl((int)cv.y, j));
          uint4 u0 = ((const uint4*)(FB + (size_t)(u32)c0 * 256))[lane];
          acc_am(am, u0, w0); acc_av(av, u0, w0 * w0);
        }
      } else {
        for (; j < rem; ++j) {
          int c0 = __shfl((int)cv.x, j);
          float w0 = __uint_as_float((u32)__shfl((int)cv.y, j));
          float4 m0 = ((const float4*)(muh  + (size_t)(u32)c0 * 256))[lane];
          float4 v0 = ((const float4*)(varh + (size_t)(u32)c0 * 256))[lane];
          float q0 = w0 * w0;
          am.x += w0 * m0.x; am.y += w0 * m0.y; am.z += w0 * m0.z; am.w += w0 * m0.w;
          av.x += q0 * v0.x; av.y += q0 * v0.y; av.z += q0 * v0.z; av.w += q0 * v0.w;
        }
      }
    }
  }

  // ---- madj ----
  {
    const int* base = base_all + 2 * (n_out + 1);
    const uint2* o = ord + 2 * (size_t)nnz;
    int b0 = base[r], b1 = base[r + 1];
    for (int s = b0; s < b1; s += 64) {
      int rem = min(64, b1 - s);
      uint2 cv = (lane < rem) ? o[s + lane] : make_uint2(0u, 0u);
      int j = 0;
      for (; j + 3 < rem; j += 4) {
        int c0 = __shfl((int)cv.x, j),     c1 = __shfl((int)cv.x, j + 1);
        int c2 = __shfl((int)cv.x, j + 2), c3 = __shfl((int)cv.x, j + 3);
        float w0 = __uint_as_float((u32)__shfl((int)cv.y, j));
        float w1 = __uint_as_float((u32)__shfl((int)cv.y, j + 1));
        float w2 = __uint_as_float((u32)__shfl((int)cv.y, j + 2));
        float w3 = __uint_as_float((u32)__shfl((int)cv.y, j + 3));
        uint2 x0 = ((const uint2*)(M + (size_t)(u32)c0 * 128))[lane];
        uint2 x1 = ((const uint2*)(M + (size_t)(u32)c1 * 128))[lane];
        uint2 x2 = ((const uint2*)(M + (size_t)(u32)c2 * 128))[lane];
        uint2 x3 = ((const uint2*)(M + (size_t)(u32)c3 * 128))[lane];
        acc_m(av, x0, w0); acc_m(av, x1, w1); acc_m(av, x2, w2); acc_m(av, x3, w3);
      }
      for (; j < rem; ++j) {
        int c0 = __shfl((int)cv.x, j);
        float w0 = __uint_as_float((u32)__shfl((int)cv.y, j));
        uint2 x0 = ((const uint2*)(M + (size_t)(u32)c0 * 128))[lane];
        acc_m(av, x0, w0);
      }
    }
  }

  // ---- epilogue: neighbour halves only, non-temporal ----
  av.x = fmaxf(av.x, 0.f) + EPS_F;
  av.y = fmaxf(av.y, 0.f) + EPS_F;
  av.z = fmaxf(av.z, 0.f) + EPS_F;
  av.w = fmaxf(av.w, 0.f) + EPS_F;
  ntstore4(out0 + (size_t)r * 512 + 256 + lane * 4, am);
  ntstore4(out1 + (size_t)r * 512 + 256 + lane * 4, av);
}

// ===========================================================================
// Fallback (tiny workspace): atomic scatter path, recompute variant.
// ===========================================================================
__global__ __launch_bounds__(256) void k_init_out(
    const float* __restrict__ mu, const float* __restrict__ var,
    float* __restrict__ out0, float* __restrict__ out1) {
  int r = blockIdx.x;
  int t = threadIdx.x;
  const float4 z = make_float4(0.f, 0.f, 0.f, 0.f);
  if (t < 128) {
    float4* dst = (float4*)(out0 + (size_t)r * 512);
    dst[t] = (t < 64) ? ((const float4*)(mu + (size_t)r * 256))[t] : z;
  } else {
    int u = t - 128;
    float4* dst = (float4*)(out1 + (size_t)r * 512);
    dst[u] = (u < 64) ? ((const float4*)(var + (size_t)r * 256))[u] : z;
  }
}

__global__ __launch_bounds__(256) void k_edge_adj_fb(
    const float* __restrict__ vals, const int* __restrict__ rows,
    const int* __restrict__ cols,
    const float* __restrict__ mu, const float* __restrict__ var,
    const float* __restrict__ muh, const float* __restrict__ varh,
    const int* __restrict__ ifield,
    float* __restrict__ out0, float* __restrict__ out1, int nnz) {
  int wave = (int)((blockIdx.x * blockDim.x + threadIdx.x) >> 6);
  int lane = threadIdx.x & 63;
  int nw = (int)((gridDim.x * blockDim.x) >> 6);
  for (int e = wave; e < nnz; e += nw) {
    float w = vals[e];
    int r = rows[e];
    int c = cols[e];
    int f = ifield[c];
    float4 m  = ((const float4*)(mu   + (size_t)c * 256))[lane];
    float4 v  = ((const float4*)(var  + (size_t)c * 256))[lane];
    float4 mh = ((const float4*)(muh  + (size_t)f * 256))[lane];
    float4 vh = ((const float4*)(varh + (size_t)f * 256))[lane];
    float4 xm, xv;
    float ds;
    xm.x = m.x - mh.x; ds = sqrtf(v.x) - sqrtf(vh.x); xv.x = ds * ds;
    xm.y = m.y - mh.y; ds = sqrtf(v.y) - sqrtf(vh.y); xv.y = ds * ds;
    xm.z = m.z - mh.z; ds = sqrtf(v.z) - sqrtf(vh.z); xv.z = ds * ds;
    xm.w = m.w - mh.w; ds = sqrtf(v.w) - sqrtf(vh.w); xv.w = ds * ds;
    float w2 = w * w;
    float* om = out0 + (size_t)r * 512 + 256 + lane * 4;
    float* ov = out1 + (size_t)r * 512 + 256 + lane * 4;
    atomicAdd(om + 0, w * xm.x); atomicAdd(om + 1, w * xm.y);
    atomicAdd(om + 2, w * xm.z); atomicAdd(om + 3, w * xm.w);
    atomicAdd(ov + 0, w2 * xv.x); atomicAdd(ov + 1, w2 * xv.y);
    atomicAdd(ov + 2, w2 * xv.z); atomicAdd(ov + 3, w2 * xv.w);
  }
}

__global__ __launch_bounds__(256) void k_edge_fadj_fb(
    const float* __restrict__ vals, const int* __restrict__ rows,
    const int* __restrict__ cols,
    const float* __restrict__ muh, const float* __restrict__ varh,
    const int* __restrict__ ffield,
    float* __restrict__ out0, float* __restrict__ out1, int nnz) {
  int wave = (int)((blockIdx.x * blockDim.x + threadIdx.x) >> 6);
  int lane = threadIdx.x & 63;
  int nw = (int)((gridDim.x * blockDim.x) >> 6);
  for (int e = wave; e < nnz; e += nw) {
    float w = vals[e];
    int r = rows[e];
    int f = ffield[cols[e]];
    float4 mb = ((const float4*)(muh  + (size_t)f * 256))[lane];
    float4 vb = ((const float4*)(varh + (size_t)f * 256))[lane];
    float w2 = w * w;
    float* om = out0 + (size_t)r * 512 + 256 + lane * 4;
    float* ov = out1 + (size_t)r * 512 + 256 + lane * 4;
    atomicAdd(om + 0, w * mb.x); atomicAdd(om + 1, w * mb.y);
    atomicAdd(om + 2, w * mb.z); atomicAdd(om + 3, w * mb.w);
    atomicAdd(ov + 0, w2 * vb.x); atomicAdd(ov + 1, w2 * vb.y);
    atomicAdd(ov + 2, w2 * vb.z); atomicAdd(ov + 3, w2 * vb.w);
  }
}

__global__ __launch_bounds__(256) void k_edge_madj_fb(
    const float* __restrict__ vals, const int* __restrict__ rows,
    const int* __restrict__ cols,
    const float* __restrict__ var, const float* __restrict__ varh,
    const int* __restrict__ ifield,
    float* __restrict__ out1, int nnz) {
  int wave = (int)((blockIdx.x * blockDim.x + threadIdx.x) >> 6);
  int lane = threadIdx.x & 63;
  int nw = (int)((gridDim.x * blockDim.x) >> 6);
  for (int e = wave; e < nnz; e += nw) {
    float w = 2.0f * vals[e];
    int r = rows[e];
    int c = cols[e];
    int f = ifield[c];
    float4 v  = ((const float4*)(var  + (size_t)c * 256))[lane];
    float4 vh = ((const float4*)(varh + (size_t)f * 256))[lane];
    float4 x;
    float sb;
    sb = sqrtf(vh.x); x.x = (sqrtf(v.x) - sb) * sb;
    sb = sqrtf(vh.y); x.y = (sqrtf(v.y) - sb) * sb;
    sb = sqrtf(vh.z); x.z = (sqrtf(v.z) - sb) * sb;
    sb = sqrtf(vh.w); x.w = (sqrtf(v.w) - sb) * sb;
    float* ov = out1 + (size_t)r * 512 + 256 + lane * 4;
    atomicAdd(ov + 0, w * x.x); atomicAdd(ov + 1, w * x.y);
    atomicAdd(ov + 2, w * x.z); atomicAdd(ov + 3, w * x.w);
  }
}

__global__ __launch_bounds__(256) void k_final(float* __restrict__ out1, int n_out) {
  int total = n_out * 64;
  for (int i = blockIdx.x * blockDim.x + threadIdx.x; i < total;
       i += gridDim.x * blockDim.x) {
    int r = i >> 6;
    int q = i & 63;
    float4* p = (float4*)(out1 + (size_t)r * 512 + 256) + q;
    float4 v = *p;
    v.x = fmaxf(v.x, 0.f) + EPS_F;
    v.y = fmaxf(v.y, 0.f) + EPS_F;
    v.z = fmaxf(v.z, 0.f) + EPS_F;
    v.w = fmaxf(v.w, 0.f) + EPS_F;
    *p = v;
  }
}

// ===========================================================================
extern "C" void kernel_launch(void* const* d_in, const int* in_sizes, int n_in_args,
                              void* d_out, int out_size, void* d_ws, size_t ws_size,
                              hipStream_t stream) {
  const float* mu        = (const float*)d_in[0];
  const float* var       = (const float*)d_in[1];
  const float* muh       = (const float*)d_in[2];
  const float* varh      = (const float*)d_in[3];
  const float* adj_vals  = (const float*)d_in[4];
  const float* fadj_vals = (const float*)d_in[5];
  const float* madj_vals = (const float*)d_in[6];
  const int* adj_rows    = (const int*)d_in[7];
  const int* adj_cols    = (const int*)d_in[8];
  const int* fadj_rows   = (const int*)d_in[9];
  const int* fadj_cols   = (const int*)d_in[10];
  const int* madj_rows   = (const int*)d_in[11];
  const int* madj_cols   = (const int*)d_in[12];
  const int* ifield      = (const int*)d_in[13];
  const int* ffield      = (const int*)d_in[14];

  const int n_out  = out_size / 1024;    // two outputs, 512 cols each
  const int n_in   = in_sizes[0] / 256;
  const int nnz    = in_sizes[4];
  const int n_full = in_sizes[14];       // ffield length

  float* out0 = (float*)d_out;
  float* out1 = out0 + (size_t)n_out * 512;

  // Workspace layout (u32 units): A, M, [FB], ord(uint2), cnt, base, cur
  const size_t uA = (size_t)n_in * 256;
  const size_t uM = (size_t)n_in * 128;
  const size_t uFB = (size_t)n_full * 256;
  const size_t uOrd = (size_t)3 * nnz * 2;
  const size_t uCnt = (size_t)3 * n_out;
  const size_t uBase = (size_t)3 * (n_out + 1);
  const size_t need2 = (uA + uM + uOrd + uCnt + uBase + uCnt) * sizeof(u32);
  const size_t need1 = need2 + uFB * sizeof(u32);

  if (ws_size >= need2) {
    const bool fb = (ws_size >= need1);
    u32* A = (u32*)d_ws;
    u32* M = A + uA;
    u32* FB = M + uM;                       // only valid if fb
    u32* tail = fb ? (FB + uFB) : (M + uM);
    uint2* ord = (uint2*)tail;
    int* cnt  = (int*)(tail + uOrd);
    int* base = cnt + uCnt;
    int* cur  = base + uBase;

    (void)hipMemsetAsync(cnt, 0, uCnt * sizeof(int), stream);
    k_count<<<1024, 256, 0, stream>>>(adj_rows, fadj_rows, madj_rows, cnt, nnz, n_out);
    k_scan3<<<3, 256, 0, stream>>>(cnt, base, cur, n_out);
    if (fb) {
      k_pre_scatter<true><<<2048, 256, 0, stream>>>(
          mu, var, muh, varh, ifield, ffield,
          adj_rows, adj_cols, adj_vals, fadj_rows, fadj_cols, fadj_vals,
          madj_rows, madj_cols, madj_vals,
          cur, ord, A, M, FB, out0, out1, n_in, n_full, n_out, nnz);
    } else {
      k_pre_scatter<false><<<2048, 256, 0, stream>>>(
          mu, var, muh, varh, ifield, ffield,
          adj_rows, adj_cols, adj_vals, fadj_rows, fadj_cols, fadj_vals,
          madj_rows, madj_cols, madj_vals,
          cur, ord, A, M, nullptr, out0, out1, n_in, n_full, n_out, nnz);
    }
    int blocks = (n_out * 64 + 255) / 256;
    if (fb) {
      k_agg<true><<<blocks, 256, 0, stream>>>(muh, varh, A, M, FB, base, ord,
                                              out0, out1, n_out, nnz);
    } else {
      k_agg<false><<<blocks, 256, 0, stream>>>(muh, varh, A, M, nullptr, base, ord,
                                               out0, out1, n_out, nnz);
    }
  } else {
    k_init_out<<<n_out, 256, 0, stream>>>(mu, var, out0, out1);
    k_edge_adj_fb<<<4096, 256, 0, stream>>>(adj_vals, adj_rows, adj_cols,
                                            mu, var, muh, varh, ifield, out0, out1, nnz);
    k_edge_madj_fb<<<4096, 256, 0, stream>>>(madj_vals, madj_rows, madj_cols,
                                             var, varh, ifield, out1, nnz);
    k_edge_fadj_fb<<<4096, 256, 0, stream>>>(fadj_vals, fadj_rows, fadj_cols,
                                             muh, varh, ffield, out0, out1, nnz);
    k_final<<<4096, 256, 0, stream>>>(out1, n_out);
  }
}